// Round 10
// baseline (223.126 us; speedup 1.0000x reference)
//
#include <hip/hip_runtime.h>

// B=4, T=2048, D=512, H=8, Dh=64. All inputs fp32.
// Outputs (concatenated in d_out): out [4,2048,512] fp32, w [4,8,2048,2048] fp32.

typedef __attribute__((ext_vector_type(4))) float f32x4;
typedef __attribute__((ext_vector_type(8))) short short8;
typedef __attribute__((ext_vector_type(8))) __bf16 bf16x8;
typedef __attribute__((ext_vector_type(2))) unsigned int uintx2;
typedef __attribute__((ext_vector_type(4))) unsigned int uintx4;

// hardware RNE f32->bf16 (compiler emits v_cvt_pk_bf16_f32 for pairs)
static __device__ __forceinline__ unsigned short bfc(float f) {
  return __builtin_bit_cast(unsigned short, (__bf16)f);
}
static __device__ __forceinline__ unsigned pkbf(float a, float b) {
  return (unsigned)bfc(a) | ((unsigned)bfc(b) << 16);
}
static __device__ __forceinline__ short8 cvt_bf8(f32x4 f0, f32x4 f1) {
  uintx4 u;
  u[0] = pkbf(f0[0], f0[1]);
  u[1] = pkbf(f0[2], f0[3]);
  u[2] = pkbf(f1[0], f1[1]);
  u[3] = pkbf(f1[2], f1[3]);
  return __builtin_bit_cast(short8, u);
}

static __device__ __forceinline__ f32x4 mfma16(short8 a, short8 b, f32x4 c) {
  return __builtin_amdgcn_mfma_f32_16x16x32_bf16(
      __builtin_bit_cast(bf16x8, a), __builtin_bit_cast(bf16x8, b), c, 0, 0, 0);
}

// async global->LDS, 16B per lane; LDS dest = wave-uniform base + lane*16
#define GLD16(gsrc, ldst)                                                     \
  __builtin_amdgcn_global_load_lds(                                           \
      (const __attribute__((address_space(1))) void*)(gsrc),                  \
      (__attribute__((address_space(3))) void*)(ldst), 16, 0, 0)

// ---------------------------------------------------------------------------
// Pre-convert fp32 -> bf16 (RNE): q,k,v (4.19M elts each) and Wq,Wk,Wv
// (262K each) into the dead `w` output region (attn overwrites it later).
// Offsets (elements): q@0, k@4194304, v@8388608, Wq@12582912, Wk@12845056,
// Wv@13107200.
// ---------------------------------------------------------------------------
__global__ __launch_bounds__(256) void cvt_kernel(
    const float* __restrict__ q, const float* __restrict__ k, const float* __restrict__ v,
    const float* __restrict__ Wq, const float* __restrict__ Wk, const float* __restrict__ Wv,
    unsigned short* __restrict__ dst) {
  const int seg = blockIdx.y;
  const float* src = seg == 0 ? q : seg == 1 ? k : seg == 2 ? v
                     : seg == 3 ? Wq : seg == 4 ? Wk : Wv;
  const size_t base = seg < 3 ? (size_t)seg * 4194304
                              : 12582912ull + (size_t)(seg - 3) * 262144;
  const size_t n = seg < 3 ? 4194304 : 262144;
  const size_t i = ((size_t)blockIdx.x * 256 + threadIdx.x) * 8;
  if (i < n) {
    const f32x4 f0 = *(const f32x4*)(src + i), f1 = *(const f32x4*)(src + i + 4);
    *(short8*)(dst + base + i) = cvt_bf8(f0, f1);
  }
}

// ---------------------------------------------------------------------------
// GEMM core, all-bf16 inputs, GLD16 staging both sides (m97 structure).
// As/Bs: [128][64] bf16 LINEAR (GLD16 dest must be contiguous); 16B slot of
// row r is filled from global chunk s^(r&7) (pre-swizzled source), reads
// apply the same XOR -> conflict-free ds_read_b128.
// ---------------------------------------------------------------------------
__device__ __forceinline__ void gemm_bf(const unsigned short* __restrict__ Xb,
                                        const unsigned short* __restrict__ Wb,
                                        short* As, short* Bs,
                                        int row0, int col0, f32x4 (&acc)[4][4]) {
  const int tid = threadIdx.x, lane = tid & 63;
  const int wv = tid >> 6, wm = wv >> 1, wn = wv & 1;
  const int g = lane >> 4, c = lane & 15, sw = c & 7;

  for (int k0 = 0; k0 < 512; k0 += 64) {
#pragma unroll
    for (int i = 0; i < 4; ++i) {
      const int gr = (wv * 4 + i) * 64 + lane;
      const int r = gr >> 3, s = gr & 7;
      GLD16(Xb + (size_t)(row0 + r) * 512 + k0 + ((s ^ (r & 7)) << 3),
            (char*)As + ((wv * 4 + i) << 10));
      GLD16(Wb + (size_t)(col0 + r) * 512 + k0 + ((s ^ (r & 7)) << 3),
            (char*)Bs + ((wv * 4 + i) << 10));
    }
    __syncthreads();
#pragma unroll
    for (int kk = 0; kk < 2; ++kk) {
      short8 a[4], b[4];
#pragma unroll
      for (int i = 0; i < 4; ++i) {
        a[i] = *(const short8*)&As[((wm * 64 + i * 16 + c) << 6) + (((kk * 4 + g) ^ sw) << 3)];
        b[i] = *(const short8*)&Bs[((wn * 64 + i * 16 + c) << 6) + (((kk * 4 + g) ^ sw) << 3)];
      }
#pragma unroll
      for (int mi = 0; mi < 4; ++mi)
#pragma unroll
        for (int ni = 0; ni < 4; ++ni) acc[mi][ni] = mfma16(a[mi], b[ni], acc[mi][ni]);
    }
    __syncthreads();
  }
}

// ---------------------------------------------------------------------------
// Fused QKV projections from the bf16 stash. z=0:Q -> headsplit bf16
// [bh][t][64], PRE-SCALED by 0.125*log2(e); z=1:K -> headsplit bf16;
// z=2:V -> TRANSPOSED bf16 [bh][dh][2048] (packed 8B stores along t).
// ---------------------------------------------------------------------------
__global__ __launch_bounds__(256) void qkv_gemm(
    const unsigned short* __restrict__ stash,
    const float* __restrict__ bq, const float* __restrict__ bk, const float* __restrict__ bv,
    unsigned short* __restrict__ Qbf, unsigned short* __restrict__ Kbf,
    unsigned short* __restrict__ Vbf) {
  __shared__ short As[128 * 64];
  __shared__ short Bs[128 * 64];
  const int z = blockIdx.z;
  const unsigned short* Xb = stash + (size_t)z * 4194304;
  const unsigned short* Wb = stash + 12582912ull + (size_t)z * 262144;
  const float* bias = z == 0 ? bq : (z == 1 ? bk : bv);
  const int row0 = blockIdx.x * 128, col0 = blockIdx.y * 128;

  f32x4 acc[4][4] = {};
  gemm_bf(Xb, Wb, As, Bs, row0, col0, acc);

  const int lane = threadIdx.x & 63;
  const int wv = threadIdx.x >> 6, wm = wv >> 1, wn = wv & 1;
  const int g = lane >> 4, c = lane & 15;

  if (z < 2) {
    unsigned short* Y = z == 0 ? Qbf : Kbf;
    const float scl = z == 0 ? 0.18033688f : 1.0f;  // 0.125 * log2(e) for Q
#pragma unroll
    for (int mi = 0; mi < 4; ++mi)
#pragma unroll
      for (int ni = 0; ni < 4; ++ni) {
        const int col = col0 + wn * 64 + ni * 16 + c;
        const float bvl = bias[col];
        const int rowb = row0 + wm * 64 + mi * 16 + g * 4;
#pragma unroll
        for (int r = 0; r < 4; ++r) {
          const int row = rowb + r;
          const int bb = row >> 11, t = row & 2047;
          const int h = col >> 6, dh = col & 63;
          Y[((size_t)((bb * 8 + h) * 2048 + t) << 6) + dh] = bfc((acc[mi][ni][r] + bvl) * scl);
        }
      }
  } else {
#pragma unroll
    for (int mi = 0; mi < 4; ++mi)
#pragma unroll
      for (int ni = 0; ni < 4; ++ni) {
        const int col = col0 + wn * 64 + ni * 16 + c;
        const float bvl = bias[col];
        const int rowb = row0 + wm * 64 + mi * 16 + g * 4;  // 4 consecutive t
        const int bb = rowb >> 11, t = rowb & 2047;
        const int h = col >> 6, dh = col & 63;
        uintx2 pk;
        pk[0] = pkbf(acc[mi][ni][0] + bvl, acc[mi][ni][1] + bvl);
        pk[1] = pkbf(acc[mi][ni][2] + bvl, acc[mi][ni][3] + bvl);
        *(uintx2*)(Vbf + ((size_t)((bb * 8 + h) * 64 + dh) * 2048 + t)) = pk;
      }
  }
}

// ---------------------------------------------------------------------------
// out = ctx @ Wo^T + bo. A (ctx bf16) via GLD16 (swizzled); B (Wo fp32)
// cvt-staged into a padded tile (small, L2-hot).
// ---------------------------------------------------------------------------
__global__ __launch_bounds__(256) void out_gemm(const unsigned short* __restrict__ ctx,
                                                const float* __restrict__ Wo,
                                                const float* __restrict__ bo,
                                                float* __restrict__ out) {
  __shared__ short As[128 * 64];
  __shared__ short Bs[128][72];
  const int tid = threadIdx.x, lane = tid & 63;
  const int wv = tid >> 6, wm = wv >> 1, wn = wv & 1;
  const int g = lane >> 4, c = lane & 15, sw = c & 7;
  const int row0 = blockIdx.x * 128, col0 = blockIdx.y * 128;

  f32x4 acc[4][4] = {};
  for (int k0 = 0; k0 < 512; k0 += 64) {
#pragma unroll
    for (int i = 0; i < 4; ++i) {
      const int gr = (wv * 4 + i) * 64 + lane;
      const int r = gr >> 3, s = gr & 7;
      GLD16(ctx + (size_t)(row0 + r) * 512 + k0 + ((s ^ (r & 7)) << 3),
            (char*)As + ((wv * 4 + i) << 10));
    }
    for (int ch = tid; ch < 1024; ch += 256) {
      const int r = ch >> 3, kc = (ch & 7) * 8;
      const float* src = Wo + (size_t)(col0 + r) * 512 + k0 + kc;
      *(short8*)&Bs[r][kc] = cvt_bf8(*(const f32x4*)src, *(const f32x4*)(src + 4));
    }
    __syncthreads();
#pragma unroll
    for (int kk = 0; kk < 2; ++kk) {
      short8 a[4], b[4];
#pragma unroll
      for (int i = 0; i < 4; ++i) {
        a[i] = *(const short8*)&As[((wm * 64 + i * 16 + c) << 6) + (((kk * 4 + g) ^ sw) << 3)];
        b[i] = *(const short8*)&Bs[wn * 64 + i * 16 + c][kk * 32 + g * 8];
      }
#pragma unroll
      for (int mi = 0; mi < 4; ++mi)
#pragma unroll
        for (int ni = 0; ni < 4; ++ni) acc[mi][ni] = mfma16(a[mi], b[ni], acc[mi][ni]);
    }
    __syncthreads();
  }

#pragma unroll
  for (int mi = 0; mi < 4; ++mi)
#pragma unroll
    for (int ni = 0; ni < 4; ++ni) {
      const int col = col0 + wn * 64 + ni * 16 + c;
      const float bvl = bo[col];
      const int rowb = row0 + wm * 64 + mi * 16 + g * 4;
#pragma unroll
      for (int r = 0; r < 4; ++r) out[(size_t)(rowb + r) * 512 + col] = acc[mi][ni][r] + bvl;
    }
}

// ---------------------------------------------------------------------------
// Attention — r8 champion structure (flat exp2-domain softmax, Q pre-scaled,
// KVBLK=128, K+V^T LDS staged/swizzled/double-buffered, paired tiles t=p and
// t=31-p, XCD-sticky bh remap) with ONE change vs r8: w stores (pass 2 +
// zero-fill) are NON-TEMPORAL. w is write-once/never-read; NT keeps the
// 537MB store stream from evicting the XCD-sticky 2MB K/V working set out
// of L2, so pass-1 prefetch and pass-2 restaging stay L2 hits.
// ---------------------------------------------------------------------------
__global__ __launch_bounds__(256) void attn_kernel(
    const unsigned short* __restrict__ Qb, const unsigned short* __restrict__ Kb,
    const unsigned short* __restrict__ Vtg, unsigned short* __restrict__ ctx,
    float* __restrict__ wout) {
  __shared__ short Kd[2][8192];     // [buf][kv 0..127][dh 0..63], swizzled
  __shared__ short Vd[2][8192];     // [buf][dh 0..63][kv 0..127], swizzled
  __shared__ short Ps[4][16][128];  // per-wave P, [q=c][kv], XOR-swizzled

  const int tid = threadIdx.x, lane = tid & 63, wv = tid >> 6;
  const int g = lane >> 4, c = lane & 15;
  const int sw = (c & 7) << 3;  // Ps swizzle (bits 3-5 of kv index)

  // XCD-aware remap: wgid%8 selects the XCD-sticky bh group
  const int wgid = blockIdx.x + (blockIdx.y << 4);  // grid (16, 32)
  const int rr_ = wgid & 31;
  const int p = wgid >> 5;                        // pair index 0..15
  const int bh = ((rr_ & 7) << 2) + (rr_ >> 3);   // bijective in 0..31

  const unsigned short* Qp = Qb + (size_t)bh * (2048 * 64);
  const unsigned short* Kp = Kb + (size_t)bh * (2048 * 64);
  const unsigned short* Vp = Vtg + (size_t)bh * (64 * 2048);
  const int b_ = bh >> 3, h_ = bh & 7;

  for (int half = 0; half < 2; ++half) {
    const int t = half ? (31 - p) : p;
    const int q0 = t * 64;
    const int jmax = t >> 1;
    const int qr = q0 + wv * 16 + c;  // this lane's q row (global)

    // protect Kd/Vd against prev half's readers, then prologue-stage tile 0
    __syncthreads();
#pragma unroll
    for (int i = 0; i < 4; ++i) {  // K tile 0
      const int gr = (wv * 4 + i) * 64 + lane;
      const int row = gr >> 3, slot = gr & 7;
      GLD16(Kp + ((size_t)row * 64) + ((slot ^ (row & 7)) << 3),
            (char*)Kd[0] + ((wv * 4 + i) << 10));
    }
#pragma unroll
    for (int i = 0; i < 4; ++i) {  // V^T tile 0
      const int gr = (wv * 4 + i) * 64 + lane;
      const int row = gr >> 4, slot = gr & 15;
      GLD16(Vp + ((size_t)row * 2048) + ((slot ^ (row & 7)) << 3),
            (char*)Vd[0] + ((wv * 4 + i) << 10));
    }

    short8 qf[2];
    qf[0] = *(const short8*)(Qp + (size_t)qr * 64 + g * 8);
    qf[1] = *(const short8*)(Qp + (size_t)qr * 64 + 32 + g * 8);

    f32x4 O[4] = {};  // lane: q = g*4+r (wave-local), dh = nd*16+c
    float l_r = 0.0f;

    // ---- pass 1 ----
    for (int j = 0; j <= jmax; ++j) {
      __syncthreads();  // tile j landed; all waves done with j-1
      if (j < jmax) {   // prefetch tile j+1 into the other buffer
        const int nb = (j + 1) & 1;
#pragma unroll
        for (int i = 0; i < 4; ++i) {
          const int gr = (wv * 4 + i) * 64 + lane;
          const int row = gr >> 3, slot = gr & 7;
          GLD16(Kp + ((size_t)((j + 1) * 128 + row) * 64) + ((slot ^ (row & 7)) << 3),
                (char*)Kd[nb] + ((wv * 4 + i) << 10));
        }
#pragma unroll
        for (int i = 0; i < 4; ++i) {
          const int gr = (wv * 4 + i) * 64 + lane;
          const int row = gr >> 4, slot = gr & 15;
          GLD16(Vp + ((size_t)row * 2048) + (j + 1) * 128 + ((slot ^ (row & 7)) << 3),
                (char*)Vd[nb] + ((wv * 4 + i) << 10));
        }
      }
      const short* Ksb = Kd[j & 1];
      const short* Vsb = Vd[j & 1];

      // S^T = K Q^T : lane (c,g): q=c, kv = nc*16 + g*4 + r  (exp2 domain)
      f32x4 S[8];
#pragma unroll
      for (int nc = 0; nc < 8; ++nc) S[nc] = (f32x4){0.f, 0.f, 0.f, 0.f};
#pragma unroll
      for (int kk = 0; kk < 2; ++kk)
#pragma unroll
        for (int nc = 0; nc < 8; ++nc) {
          const int row = nc * 16 + c;
          const short8 kf = *(const short8*)&Ksb[row * 64 + (((kk * 4 + g) ^ (c & 7)) << 3)];
          S[nc] = mfma16(kf, qf[kk], S[nc]);
        }

      // flat softmax numerator: P = exp2(S); mask only on the diagonal tile
      f32x4 ssum = {0.f, 0.f, 0.f, 0.f};
      if (j == jmax) {
        const int kvb = j * 128 + g * 4;
#pragma unroll
        for (int nc = 0; nc < 8; ++nc) {
#pragma unroll
          for (int r = 0; r < 4; ++r) {
            float val = __builtin_amdgcn_exp2f(S[nc][r]);
            if (kvb + nc * 16 + r > qr) val = 0.f;
            S[nc][r] = val;
          }
          ssum += S[nc];
        }
      } else {
#pragma unroll
        for (int nc = 0; nc < 8; ++nc) {
#pragma unroll
          for (int r = 0; r < 4; ++r) S[nc][r] = __builtin_amdgcn_exp2f(S[nc][r]);
          ssum += S[nc];
        }
      }
      l_r += ssum[0] + ssum[1] + ssum[2] + ssum[3];

      // P -> LDS (bf16 pairs, XOR-swizzled; wave-private rows, no barrier)
#pragma unroll
      for (int nc = 0; nc < 8; ++nc) {
        uintx2 pk;
        pk[0] = pkbf(S[nc][0], S[nc][1]);
        pk[1] = pkbf(S[nc][2], S[nc][3]);
        *(uintx2*)&Ps[wv][c][(nc * 16 + g * 4) ^ sw] = pk;
      }

      // O += P V  (A=P: q=c, kv contig; B=V^T: dh=c, kv contig)
#pragma unroll
      for (int kk2 = 0; kk2 < 4; ++kk2) {
        const short8 pa = *(const short8*)&Ps[wv][c][(kk2 * 32 + g * 8) ^ sw];
#pragma unroll
        for (int nd = 0; nd < 4; ++nd) {
          const int row = nd * 16 + c;
          const short8 vb = *(const short8*)&Vsb[row * 128 + (((kk2 * 4 + g) ^ (c & 7)) << 3)];
          O[nd] = mfma16(pa, vb, O[nd]);
        }
      }
    }

    // finalize l: combine the 4 g-lane partials (once per tile, not per step)
    l_r += __shfl_xor(l_r, 16);
    l_r += __shfl_xor(l_r, 32);

    // normalize + write context bf16 [B][T][512]
    {
      float lv[4];
#pragma unroll
      for (int r = 0; r < 4; ++r) lv[r] = __shfl(l_r, g * 4 + r);
#pragma unroll
      for (int r = 0; r < 4; ++r) {
        const float inv = 1.0f / lv[r];
        const int trow = q0 + wv * 16 + g * 4 + r;
        unsigned short* cp = ctx + ((size_t)(b_ * 2048 + trow) * 512) + h_ * 64;
#pragma unroll
        for (int nd = 0; nd < 4; ++nd) cp[nd * 16 + c] = bfc(O[nd][r] * inv);
      }
    }

    // ---- pass 2: w = exp2(S)/l, NT dwordx4 stores; j descending reuses the
    // last K tile (live in Kd[jmax&1]); double-buffered prefetch of j-1.
    const float inv_l = 1.0f / l_r;
    float* wbase = wout + ((size_t)bh * 2048 + q0) * 2048;
    for (int j = jmax; j >= 0; --j) {
      __syncthreads();  // prefetch landed; all waves done with tile j+1
      if (j > 0) {      // prefetch tile j-1 into the other buffer
#pragma unroll
        for (int i = 0; i < 4; ++i) {
          const int gr = (wv * 4 + i) * 64 + lane;
          const int row = gr >> 3, slot = gr & 7;
          GLD16(Kp + ((size_t)((j - 1) * 128 + row) * 64) + ((slot ^ (row & 7)) << 3),
                (char*)Kd[(j - 1) & 1] + ((wv * 4 + i) << 10));
        }
      }
      const short* Ksb = Kd[j & 1];

      f32x4 S[8];
#pragma unroll
      for (int nc = 0; nc < 8; ++nc) S[nc] = (f32x4){0.f, 0.f, 0.f, 0.f};
#pragma unroll
      for (int kk = 0; kk < 2; ++kk)
#pragma unroll
        for (int nc = 0; nc < 8; ++nc) {
          const int row = nc * 16 + c;
          const short8 kf = *(const short8*)&Ksb[row * 64 + (((kk * 4 + g) ^ (c & 7)) << 3)];
          S[nc] = mfma16(kf, qf[kk], S[nc]);
        }

      const bool lastj = (j == jmax);
      float* wr = wbase + (size_t)(wv * 16 + c) * 2048 + j * 128;
#pragma unroll
      for (int nc = 0; nc < 8; ++nc) {
        f32x4 w4;
#pragma unroll
        for (int r = 0; r < 4; ++r) {
          float val = __builtin_amdgcn_exp2f(S[nc][r]) * inv_l;
          if (lastj && (j * 128 + nc * 16 + g * 4 + r > qr)) val = 0.f;
          w4[r] = val;
        }
        __builtin_nontemporal_store(w4, (f32x4*)(wr + nc * 16 + g * 4));
      }
    }

    // zero-fill strictly-causal-empty region (non-temporal)
    {
      const int c0 = (jmax + 1) * 128;
      const f32x4 z = {0.f, 0.f, 0.f, 0.f};
      for (int rr = wv; rr < 64; rr += 4) {
        float* rp = wbase + (size_t)rr * 2048;
        for (int x = c0 + lane * 4; x < 2048; x += 256)
          __builtin_nontemporal_store(z, (f32x4*)(rp + x));
      }
    }
  }
}

// ---------------------------------------------------------------------------
extern "C" void kernel_launch(void* const* d_in, const int* in_sizes, int n_in,
                              void* d_out, int out_size, void* d_ws, size_t ws_size,
                              hipStream_t stream) {
  const float* q  = (const float*)d_in[0];
  const float* k  = (const float*)d_in[1];
  const float* v  = (const float*)d_in[2];
  const float* Wq = (const float*)d_in[3];
  const float* bq = (const float*)d_in[4];
  const float* Wk = (const float*)d_in[5];
  const float* bk = (const float*)d_in[6];
  const float* Wv = (const float*)d_in[7];
  const float* bv = (const float*)d_in[8];
  const float* Wo = (const float*)d_in[9];
  const float* bo = (const float*)d_in[10];

  // ws: Qbf,Kbf [bh][t][64] bf16; Vbf [bh][dh][2048] bf16; ctx [8192][512] bf16
  unsigned short* Qbf = (unsigned short*)d_ws;
  unsigned short* Kbf = Qbf + (size_t)4194304;
  unsigned short* Vbf = Kbf + (size_t)4194304;
  unsigned short* ctx = Vbf + (size_t)4194304;

  float* out  = (float*)d_out;
  float* wout = out + (size_t)4 * 2048 * 512;
  // bf16 stash for q,k,v,Wq,Wk,Wv lives in the (dead until attn) w region
  unsigned short* stash = (unsigned short*)wout;

  cvt_kernel<<<dim3(2048, 6), 256, 0, stream>>>(q, k, v, Wq, Wk, Wv, stash);
  qkv_gemm<<<dim3(64, 4, 3), 256, 0, stream>>>(stash, bq, bk, bv, Qbf, Kbf, Vbf);
  attn_kernel<<<dim3(16, 32), 256, 0, stream>>>(Qbf, Kbf, Vbf, ctx, wout);
  out_gemm<<<dim3(64, 4), 256, 0, stream>>>(ctx, Wo, bo, out);
}

// Round 11
// 194.762 us; speedup vs baseline: 1.1456x; 1.1456x over previous
//
#include <hip/hip_runtime.h>

// B=4, T=2048, D=512, H=8, Dh=64. All inputs fp32.
// Outputs (concatenated in d_out): out [4,2048,512] fp32, w [4,8,2048,2048] fp32.

typedef __attribute__((ext_vector_type(4))) float f32x4;
typedef __attribute__((ext_vector_type(8))) short short8;
typedef __attribute__((ext_vector_type(8))) __bf16 bf16x8;
typedef __attribute__((ext_vector_type(2))) unsigned int uintx2;
typedef __attribute__((ext_vector_type(4))) unsigned int uintx4;

// hardware RNE f32->bf16 (compiler emits v_cvt_pk_bf16_f32 for pairs)
static __device__ __forceinline__ unsigned short bfc(float f) {
  return __builtin_bit_cast(unsigned short, (__bf16)f);
}
static __device__ __forceinline__ unsigned pkbf(float a, float b) {
  return (unsigned)bfc(a) | ((unsigned)bfc(b) << 16);
}
static __device__ __forceinline__ short8 cvt_bf8(f32x4 f0, f32x4 f1) {
  uintx4 u;
  u[0] = pkbf(f0[0], f0[1]);
  u[1] = pkbf(f0[2], f0[3]);
  u[2] = pkbf(f1[0], f1[1]);
  u[3] = pkbf(f1[2], f1[3]);
  return __builtin_bit_cast(short8, u);
}

static __device__ __forceinline__ f32x4 mfma16(short8 a, short8 b, f32x4 c) {
  return __builtin_amdgcn_mfma_f32_16x16x32_bf16(
      __builtin_bit_cast(bf16x8, a), __builtin_bit_cast(bf16x8, b), c, 0, 0, 0);
}

// async global->LDS, 16B per lane; LDS dest = wave-uniform base + lane*16
#define GLD16(gsrc, ldst)                                                     \
  __builtin_amdgcn_global_load_lds(                                           \
      (const __attribute__((address_space(1))) void*)(gsrc),                  \
      (__attribute__((address_space(3))) void*)(ldst), 16, 0, 0)

// ---------------------------------------------------------------------------
// Pre-convert fp32 -> bf16 (RNE): q,k,v (4.19M elts each) and Wq,Wk,Wv
// (262K each) into the dead `w` output region (attn overwrites it later).
// Offsets (elements): q@0, k@4194304, v@8388608, Wq@12582912, Wk@12845056,
// Wv@13107200.
// ---------------------------------------------------------------------------
__global__ __launch_bounds__(256) void cvt_kernel(
    const float* __restrict__ q, const float* __restrict__ k, const float* __restrict__ v,
    const float* __restrict__ Wq, const float* __restrict__ Wk, const float* __restrict__ Wv,
    unsigned short* __restrict__ dst) {
  const int seg = blockIdx.y;
  const float* src = seg == 0 ? q : seg == 1 ? k : seg == 2 ? v
                     : seg == 3 ? Wq : seg == 4 ? Wk : Wv;
  const size_t base = seg < 3 ? (size_t)seg * 4194304
                              : 12582912ull + (size_t)(seg - 3) * 262144;
  const size_t n = seg < 3 ? 4194304 : 262144;
  const size_t i = ((size_t)blockIdx.x * 256 + threadIdx.x) * 8;
  if (i < n) {
    const f32x4 f0 = *(const f32x4*)(src + i), f1 = *(const f32x4*)(src + i + 4);
    *(short8*)(dst + base + i) = cvt_bf8(f0, f1);
  }
}

// ---------------------------------------------------------------------------
// GEMM core, all-bf16 inputs, GLD16 staging both sides (m97 structure).
// As/Bs: [128][64] bf16 LINEAR (GLD16 dest must be contiguous); 16B slot of
// row r is filled from global chunk s^(r&7) (pre-swizzled source), reads
// apply the same XOR -> conflict-free ds_read_b128.
// ---------------------------------------------------------------------------
__device__ __forceinline__ void gemm_bf(const unsigned short* __restrict__ Xb,
                                        const unsigned short* __restrict__ Wb,
                                        short* As, short* Bs,
                                        int row0, int col0, f32x4 (&acc)[4][4]) {
  const int tid = threadIdx.x, lane = tid & 63;
  const int wv = tid >> 6, wm = wv >> 1, wn = wv & 1;
  const int g = lane >> 4, c = lane & 15, sw = c & 7;

  for (int k0 = 0; k0 < 512; k0 += 64) {
#pragma unroll
    for (int i = 0; i < 4; ++i) {
      const int gr = (wv * 4 + i) * 64 + lane;
      const int r = gr >> 3, s = gr & 7;
      GLD16(Xb + (size_t)(row0 + r) * 512 + k0 + ((s ^ (r & 7)) << 3),
            (char*)As + ((wv * 4 + i) << 10));
      GLD16(Wb + (size_t)(col0 + r) * 512 + k0 + ((s ^ (r & 7)) << 3),
            (char*)Bs + ((wv * 4 + i) << 10));
    }
    __syncthreads();
#pragma unroll
    for (int kk = 0; kk < 2; ++kk) {
      short8 a[4], b[4];
#pragma unroll
      for (int i = 0; i < 4; ++i) {
        a[i] = *(const short8*)&As[((wm * 64 + i * 16 + c) << 6) + (((kk * 4 + g) ^ sw) << 3)];
        b[i] = *(const short8*)&Bs[((wn * 64 + i * 16 + c) << 6) + (((kk * 4 + g) ^ sw) << 3)];
      }
#pragma unroll
      for (int mi = 0; mi < 4; ++mi)
#pragma unroll
        for (int ni = 0; ni < 4; ++ni) acc[mi][ni] = mfma16(a[mi], b[ni], acc[mi][ni]);
    }
    __syncthreads();
  }
}

// ---------------------------------------------------------------------------
// Fused QKV projections from the bf16 stash. z=0:Q -> headsplit bf16
// [bh][t][64], PRE-SCALED by 0.125*log2(e); z=1:K -> headsplit bf16;
// z=2:V -> TRANSPOSED bf16 [bh][dh][2048] (packed 8B stores along t).
// ---------------------------------------------------------------------------
__global__ __launch_bounds__(256) void qkv_gemm(
    const unsigned short* __restrict__ stash,
    const float* __restrict__ bq, const float* __restrict__ bk, const float* __restrict__ bv,
    unsigned short* __restrict__ Qbf, unsigned short* __restrict__ Kbf,
    unsigned short* __restrict__ Vbf) {
  __shared__ short As[128 * 64];
  __shared__ short Bs[128 * 64];
  const int z = blockIdx.z;
  const unsigned short* Xb = stash + (size_t)z * 4194304;
  const unsigned short* Wb = stash + 12582912ull + (size_t)z * 262144;
  const float* bias = z == 0 ? bq : (z == 1 ? bk : bv);
  const int row0 = blockIdx.x * 128, col0 = blockIdx.y * 128;

  f32x4 acc[4][4] = {};
  gemm_bf(Xb, Wb, As, Bs, row0, col0, acc);

  const int lane = threadIdx.x & 63;
  const int wv = threadIdx.x >> 6, wm = wv >> 1, wn = wv & 1;
  const int g = lane >> 4, c = lane & 15;

  if (z < 2) {
    unsigned short* Y = z == 0 ? Qbf : Kbf;
    const float scl = z == 0 ? 0.18033688f : 1.0f;  // 0.125 * log2(e) for Q
#pragma unroll
    for (int mi = 0; mi < 4; ++mi)
#pragma unroll
      for (int ni = 0; ni < 4; ++ni) {
        const int col = col0 + wn * 64 + ni * 16 + c;
        const float bvl = bias[col];
        const int rowb = row0 + wm * 64 + mi * 16 + g * 4;
#pragma unroll
        for (int r = 0; r < 4; ++r) {
          const int row = rowb + r;
          const int bb = row >> 11, t = row & 2047;
          const int h = col >> 6, dh = col & 63;
          Y[((size_t)((bb * 8 + h) * 2048 + t) << 6) + dh] = bfc((acc[mi][ni][r] + bvl) * scl);
        }
      }
  } else {
#pragma unroll
    for (int mi = 0; mi < 4; ++mi)
#pragma unroll
      for (int ni = 0; ni < 4; ++ni) {
        const int col = col0 + wn * 64 + ni * 16 + c;
        const float bvl = bias[col];
        const int rowb = row0 + wm * 64 + mi * 16 + g * 4;  // 4 consecutive t
        const int bb = rowb >> 11, t = rowb & 2047;
        const int h = col >> 6, dh = col & 63;
        uintx2 pk;
        pk[0] = pkbf(acc[mi][ni][0] + bvl, acc[mi][ni][1] + bvl);
        pk[1] = pkbf(acc[mi][ni][2] + bvl, acc[mi][ni][3] + bvl);
        *(uintx2*)(Vbf + ((size_t)((bb * 8 + h) * 64 + dh) * 2048 + t)) = pk;
      }
  }
}

// ---------------------------------------------------------------------------
// out = ctx @ Wo^T + bo. A (ctx bf16) via GLD16 (swizzled); B (Wo fp32)
// cvt-staged into a padded tile (small, L2-hot).
// ---------------------------------------------------------------------------
__global__ __launch_bounds__(256) void out_gemm(const unsigned short* __restrict__ ctx,
                                                const float* __restrict__ Wo,
                                                const float* __restrict__ bo,
                                                float* __restrict__ out) {
  __shared__ short As[128 * 64];
  __shared__ short Bs[128][72];
  const int tid = threadIdx.x, lane = tid & 63;
  const int wv = tid >> 6, wm = wv >> 1, wn = wv & 1;
  const int g = lane >> 4, c = lane & 15, sw = c & 7;
  const int row0 = blockIdx.x * 128, col0 = blockIdx.y * 128;

  f32x4 acc[4][4] = {};
  for (int k0 = 0; k0 < 512; k0 += 64) {
#pragma unroll
    for (int i = 0; i < 4; ++i) {
      const int gr = (wv * 4 + i) * 64 + lane;
      const int r = gr >> 3, s = gr & 7;
      GLD16(ctx + (size_t)(row0 + r) * 512 + k0 + ((s ^ (r & 7)) << 3),
            (char*)As + ((wv * 4 + i) << 10));
    }
    for (int ch = tid; ch < 1024; ch += 256) {
      const int r = ch >> 3, kc = (ch & 7) * 8;
      const float* src = Wo + (size_t)(col0 + r) * 512 + k0 + kc;
      *(short8*)&Bs[r][kc] = cvt_bf8(*(const f32x4*)src, *(const f32x4*)(src + 4));
    }
    __syncthreads();
#pragma unroll
    for (int kk = 0; kk < 2; ++kk) {
      short8 a[4], b[4];
#pragma unroll
      for (int i = 0; i < 4; ++i) {
        a[i] = *(const short8*)&As[((wm * 64 + i * 16 + c) << 6) + (((kk * 4 + g) ^ sw) << 3)];
        b[i] = *(const short8*)&Bs[wn * 64 + i * 16 + c][kk * 32 + g * 8];
      }
#pragma unroll
      for (int mi = 0; mi < 4; ++mi)
#pragma unroll
        for (int ni = 0; ni < 4; ++ni) acc[mi][ni] = mfma16(a[mi], b[ni], acc[mi][ni]);
    }
    __syncthreads();
  }

#pragma unroll
  for (int mi = 0; mi < 4; ++mi)
#pragma unroll
    for (int ni = 0; ni < 4; ++ni) {
      const int col = col0 + wn * 64 + ni * 16 + c;
      const float bvl = bo[col];
      const int rowb = row0 + wm * 64 + mi * 16 + g * 4;
#pragma unroll
      for (int r = 0; r < 4; ++r) out[(size_t)(rowb + r) * 512 + col] = acc[mi][ni][r] + bvl;
    }
}

// ---------------------------------------------------------------------------
// Attention — r8 champion structure (flat exp2-domain softmax, Q pre-scaled,
// KVBLK=128, K+V^T LDS staged/swizzled/double-buffered, paired tiles t=p and
// t=31-p, XCD-sticky bh remap) with ONE change vs r8: COALESCED w STORES.
// The old pass-2 store had consecutive lanes 8KB apart (16 scattered 64B
// segments per wave instruction). Now: w values go through the idle Vd LDS
// (recast as a 64x128 f32 tile, 16B-granule XOR swizzle = the proven GEMM
// ds pattern), then a flat copy where consecutive threads store consecutive
// 16B -> 512B contiguous segments, dwordx4. Costs +1 barrier + LDS
// round-trip per step; K prefetch is issued after the mid barrier so it
// lands under the store phase.
// ---------------------------------------------------------------------------
__global__ __launch_bounds__(256) void attn_kernel(
    const unsigned short* __restrict__ Qb, const unsigned short* __restrict__ Kb,
    const unsigned short* __restrict__ Vtg, unsigned short* __restrict__ ctx,
    float* __restrict__ wout) {
  __shared__ short Kd[2][8192];     // [buf][kv 0..127][dh 0..63], swizzled
  __shared__ short Vd[2][8192];     // pass1: V^T tiles; pass2: 64x128 f32 w-stage
  __shared__ short Ps[4][16][128];  // per-wave P, [q=c][kv], XOR-swizzled

  const int tid = threadIdx.x, lane = tid & 63, wv = tid >> 6;
  const int g = lane >> 4, c = lane & 15;
  const int sw = (c & 7) << 3;  // Ps swizzle (bits 3-5 of kv index)

  // XCD-aware remap: wgid%8 selects the XCD-sticky bh group
  const int wgid = blockIdx.x + (blockIdx.y << 4);  // grid (16, 32)
  const int rr_ = wgid & 31;
  const int p = wgid >> 5;                        // pair index 0..15
  const int bh = ((rr_ & 7) << 2) + (rr_ >> 3);   // bijective in 0..31

  const unsigned short* Qp = Qb + (size_t)bh * (2048 * 64);
  const unsigned short* Kp = Kb + (size_t)bh * (2048 * 64);
  const unsigned short* Vp = Vtg + (size_t)bh * (64 * 2048);
  const int b_ = bh >> 3, h_ = bh & 7;

  for (int half = 0; half < 2; ++half) {
    const int t = half ? (31 - p) : p;
    const int q0 = t * 64;
    const int jmax = t >> 1;
    const int qr = q0 + wv * 16 + c;  // this lane's q row (global)

    // protect Kd/Vd against prev half's readers, then prologue-stage tile 0
    __syncthreads();
#pragma unroll
    for (int i = 0; i < 4; ++i) {  // K tile 0
      const int gr = (wv * 4 + i) * 64 + lane;
      const int row = gr >> 3, slot = gr & 7;
      GLD16(Kp + ((size_t)row * 64) + ((slot ^ (row & 7)) << 3),
            (char*)Kd[0] + ((wv * 4 + i) << 10));
    }
#pragma unroll
    for (int i = 0; i < 4; ++i) {  // V^T tile 0
      const int gr = (wv * 4 + i) * 64 + lane;
      const int row = gr >> 4, slot = gr & 15;
      GLD16(Vp + ((size_t)row * 2048) + ((slot ^ (row & 7)) << 3),
            (char*)Vd[0] + ((wv * 4 + i) << 10));
    }

    short8 qf[2];
    qf[0] = *(const short8*)(Qp + (size_t)qr * 64 + g * 8);
    qf[1] = *(const short8*)(Qp + (size_t)qr * 64 + 32 + g * 8);

    f32x4 O[4] = {};  // lane: q = g*4+r (wave-local), dh = nd*16+c
    float l_r = 0.0f;

    // ---- pass 1 ----
    for (int j = 0; j <= jmax; ++j) {
      __syncthreads();  // tile j landed; all waves done with j-1
      if (j < jmax) {   // prefetch tile j+1 into the other buffer
        const int nb = (j + 1) & 1;
#pragma unroll
        for (int i = 0; i < 4; ++i) {
          const int gr = (wv * 4 + i) * 64 + lane;
          const int row = gr >> 3, slot = gr & 7;
          GLD16(Kp + ((size_t)((j + 1) * 128 + row) * 64) + ((slot ^ (row & 7)) << 3),
                (char*)Kd[nb] + ((wv * 4 + i) << 10));
        }
#pragma unroll
        for (int i = 0; i < 4; ++i) {
          const int gr = (wv * 4 + i) * 64 + lane;
          const int row = gr >> 4, slot = gr & 15;
          GLD16(Vp + ((size_t)row * 2048) + (j + 1) * 128 + ((slot ^ (row & 7)) << 3),
                (char*)Vd[nb] + ((wv * 4 + i) << 10));
        }
      }
      const short* Ksb = Kd[j & 1];
      const short* Vsb = Vd[j & 1];

      // S^T = K Q^T : lane (c,g): q=c, kv = nc*16 + g*4 + r  (exp2 domain)
      f32x4 S[8];
#pragma unroll
      for (int nc = 0; nc < 8; ++nc) S[nc] = (f32x4){0.f, 0.f, 0.f, 0.f};
#pragma unroll
      for (int kk = 0; kk < 2; ++kk)
#pragma unroll
        for (int nc = 0; nc < 8; ++nc) {
          const int row = nc * 16 + c;
          const short8 kf = *(const short8*)&Ksb[row * 64 + (((kk * 4 + g) ^ (c & 7)) << 3)];
          S[nc] = mfma16(kf, qf[kk], S[nc]);
        }

      // flat softmax numerator: P = exp2(S); mask only on the diagonal tile
      f32x4 ssum = {0.f, 0.f, 0.f, 0.f};
      if (j == jmax) {
        const int kvb = j * 128 + g * 4;
#pragma unroll
        for (int nc = 0; nc < 8; ++nc) {
#pragma unroll
          for (int r = 0; r < 4; ++r) {
            float val = __builtin_amdgcn_exp2f(S[nc][r]);
            if (kvb + nc * 16 + r > qr) val = 0.f;
            S[nc][r] = val;
          }
          ssum += S[nc];
        }
      } else {
#pragma unroll
        for (int nc = 0; nc < 8; ++nc) {
#pragma unroll
          for (int r = 0; r < 4; ++r) S[nc][r] = __builtin_amdgcn_exp2f(S[nc][r]);
          ssum += S[nc];
        }
      }
      l_r += ssum[0] + ssum[1] + ssum[2] + ssum[3];

      // P -> LDS (bf16 pairs, XOR-swizzled; wave-private rows, no barrier)
#pragma unroll
      for (int nc = 0; nc < 8; ++nc) {
        uintx2 pk;
        pk[0] = pkbf(S[nc][0], S[nc][1]);
        pk[1] = pkbf(S[nc][2], S[nc][3]);
        *(uintx2*)&Ps[wv][c][(nc * 16 + g * 4) ^ sw] = pk;
      }

      // O += P V  (A=P: q=c, kv contig; B=V^T: dh=c, kv contig)
#pragma unroll
      for (int kk2 = 0; kk2 < 4; ++kk2) {
        const short8 pa = *(const short8*)&Ps[wv][c][(kk2 * 32 + g * 8) ^ sw];
#pragma unroll
        for (int nd = 0; nd < 4; ++nd) {
          const int row = nd * 16 + c;
          const short8 vb = *(const short8*)&Vsb[row * 128 + (((kk2 * 4 + g) ^ (c & 7)) << 3)];
          O[nd] = mfma16(pa, vb, O[nd]);
        }
      }
    }

    // finalize l: combine the 4 g-lane partials (once per tile, not per step)
    l_r += __shfl_xor(l_r, 16);
    l_r += __shfl_xor(l_r, 32);

    // normalize + write context bf16 [B][T][512]
    {
      float lv[4];
#pragma unroll
      for (int r = 0; r < 4; ++r) lv[r] = __shfl(l_r, g * 4 + r);
#pragma unroll
      for (int r = 0; r < 4; ++r) {
        const float inv = 1.0f / lv[r];
        const int trow = q0 + wv * 16 + g * 4 + r;
        unsigned short* cp = ctx + ((size_t)(b_ * 2048 + trow) * 512) + h_ * 64;
#pragma unroll
        for (int nd = 0; nd < 4; ++nd) cp[nd * 16 + c] = bfc(O[nd][r] * inv);
      }
    }

    // ---- pass 2: w = exp2(S)/l, COALESCED via LDS transpose; j descending
    // reuses the last K tile (live in Kd[jmax&1]); prefetch after mid barrier.
    const float inv_l = 1.0f / l_r;
    float* wbase = wout + ((size_t)bh * 2048 + q0) * 2048;
    float* Vf = (float*)Vd;  // 64x128 f32 staging tile (32KB), idle in pass 2
    for (int j = jmax; j >= 0; --j) {
      __syncthreads();  // K tile landed; Vf flat-copy of prev step complete
      const short* Ksb = Kd[j & 1];

      f32x4 S[8];
#pragma unroll
      for (int nc = 0; nc < 8; ++nc) S[nc] = (f32x4){0.f, 0.f, 0.f, 0.f};
#pragma unroll
      for (int kk = 0; kk < 2; ++kk)
#pragma unroll
        for (int nc = 0; nc < 8; ++nc) {
          const int row = nc * 16 + c;
          const short8 kf = *(const short8*)&Ksb[row * 64 + (((kk * 4 + g) ^ (c & 7)) << 3)];
          S[nc] = mfma16(kf, qf[kk], S[nc]);
        }

      const bool lastj = (j == jmax);
      // w values -> LDS f32 tile [row=wv*16+c][granule (nc*4+g)^(c&7)]
#pragma unroll
      for (int nc = 0; nc < 8; ++nc) {
        f32x4 w4;
#pragma unroll
        for (int r = 0; r < 4; ++r) {
          float val = __builtin_amdgcn_exp2f(S[nc][r]) * inv_l;
          if (lastj && (j * 128 + nc * 16 + g * 4 + r > qr)) val = 0.f;
          w4[r] = val;
        }
        const int gi = (nc * 4 + g) ^ (c & 7);
        *(f32x4*)&Vf[((wv * 16 + c) << 7) + (gi << 2)] = w4;
      }
      __syncthreads();  // w tile complete in LDS

      if (j > 0) {  // prefetch K j-1; lands under the store phase
#pragma unroll
        for (int i = 0; i < 4; ++i) {
          const int gr = (wv * 4 + i) * 64 + lane;
          const int row = gr >> 3, slot = gr & 7;
          GLD16(Kp + ((size_t)((j - 1) * 128 + row) * 64) + ((slot ^ (row & 7)) << 3),
                (char*)Kd[(j - 1) & 1] + ((wv * 4 + i) << 10));
        }
      }

      // flat coalesced copy: consecutive threads -> consecutive 16B granules
      // (512B contiguous per row segment, dwordx4)
#pragma unroll
      for (int i = 0; i < 8; ++i) {
        const int f = tid + i * 256;
        const int row = f >> 5, go = f & 31;
        const f32x4 val = *(const f32x4*)&Vf[(row << 7) + ((go ^ (row & 7)) << 2)];
        *(f32x4*)(wbase + (size_t)row * 2048 + j * 128 + go * 4) = val;
      }
    }

    // zero-fill strictly-causal-empty region (already coalesced)
    {
      const int c0 = (jmax + 1) * 128;
      const f32x4 z = {0.f, 0.f, 0.f, 0.f};
      for (int rr = wv; rr < 64; rr += 4) {
        float* rp = wbase + (size_t)rr * 2048;
        for (int x = c0 + lane * 4; x < 2048; x += 256) *(f32x4*)(rp + x) = z;
      }
    }
  }
}

// ---------------------------------------------------------------------------
extern "C" void kernel_launch(void* const* d_in, const int* in_sizes, int n_in,
                              void* d_out, int out_size, void* d_ws, size_t ws_size,
                              hipStream_t stream) {
  const float* q  = (const float*)d_in[0];
  const float* k  = (const float*)d_in[1];
  const float* v  = (const float*)d_in[2];
  const float* Wq = (const float*)d_in[3];
  const float* bq = (const float*)d_in[4];
  const float* Wk = (const float*)d_in[5];
  const float* bk = (const float*)d_in[6];
  const float* Wv = (const float*)d_in[7];
  const float* bv = (const float*)d_in[8];
  const float* Wo = (const float*)d_in[9];
  const float* bo = (const float*)d_in[10];

  // ws: Qbf,Kbf [bh][t][64] bf16; Vbf [bh][dh][2048] bf16; ctx [8192][512] bf16
  unsigned short* Qbf = (unsigned short*)d_ws;
  unsigned short* Kbf = Qbf + (size_t)4194304;
  unsigned short* Vbf = Kbf + (size_t)4194304;
  unsigned short* ctx = Vbf + (size_t)4194304;

  float* out  = (float*)d_out;
  float* wout = out + (size_t)4 * 2048 * 512;
  // bf16 stash for q,k,v,Wq,Wk,Wv lives in the (dead until attn) w region
  unsigned short* stash = (unsigned short*)wout;

  cvt_kernel<<<dim3(2048, 6), 256, 0, stream>>>(q, k, v, Wq, Wk, Wv, stash);
  qkv_gemm<<<dim3(64, 4, 3), 256, 0, stream>>>(stash, bq, bk, bv, Qbf, Kbf, Vbf);
  attn_kernel<<<dim3(16, 32), 256, 0, stream>>>(Qbf, Kbf, Vbf, ctx, wout);
  out_gemm<<<dim3(64, 4), 256, 0, stream>>>(ctx, Wo, bo, out);
}